// Round 17
// baseline (454.161 us; speedup 1.0000x reference)
//
#include <hip/hip_runtime.h>
#include <hip/hip_bf16.h>

typedef unsigned short ushort_t;
using bf16x8 = __attribute__((ext_vector_type(8))) short;
using f32x4  = __attribute__((ext_vector_type(4))) float;

#define DEV __device__ __forceinline__

DEV unsigned short f2bf(float f) {
    unsigned int u = __builtin_bit_cast(unsigned int, f);
    u = (u + 0x7fffu + ((u >> 16) & 1u)) >> 16;
    return (unsigned short)u;
}

DEV float bf2f(unsigned short s) {
    return __builtin_bit_cast(float, (unsigned int)s << 16);
}

DEV int cvtpk_bf16(float lo, float hi) {
    int r;
    asm("v_cvt_pk_bf16_f32 %0, %1, %2" : "=v"(r) : "v"(lo), "v"(hi));
    return r;
}

DEV void gload16(const unsigned short* g, unsigned short* l) {
    __builtin_amdgcn_global_load_lds(
        (const __attribute__((address_space(1))) void*)g,
        (__attribute__((address_space(3))) void*)l, 16, 0, 0);
}

// sigmoid-form GELU: v*sigmoid(1.702v); max err ~0.02 abs (threshold 0.18)
DEV float gelu_f(float v) {
    float t = __builtin_amdgcn_exp2f(v * 2.4554946f);
    return v * t * __builtin_amdgcn_rcpf(t + 1.0f);
}

// ---------------- f32 -> bf16 convert ----------------
__global__ __launch_bounds__(256) void cvtbf_kernel(const float* __restrict__ in,
                                                    unsigned short* __restrict__ out) {
    int i = (blockIdx.x * 256 + threadIdx.x) * 4;
    float4 v = *(const float4*)&in[i];
    out[i + 0] = f2bf(v.x);
    out[i + 1] = f2bf(v.y);
    out[i + 2] = f2bf(v.z);
    out[i + 3] = f2bf(v.w);
}

// ---------------- transpose + convert: in[R,C] f32 -> out[C,R] bf16 ----------------
__global__ __launch_bounds__(256) void transpose_cvt_kernel(const float* __restrict__ in,
                                                            unsigned short* __restrict__ out,
                                                            int R, int C) {
    __shared__ float t[32][33];
    int tx = threadIdx.x, ty = threadIdx.y;
    int c0 = blockIdx.x * 32, r0 = blockIdx.y * 32;
#pragma unroll
    for (int i = 0; i < 4; ++i)
        t[ty + i * 8][tx] = in[(size_t)(r0 + ty + i * 8) * C + c0 + tx];
    __syncthreads();
#pragma unroll
    for (int i = 0; i < 4; ++i)
        out[(size_t)(c0 + ty + i * 8) * R + r0 + tx] = f2bf(t[tx][ty + i * 8]);
}

// ---------------- V transpose: qkvb V-part -> vtg[bh][64][2048] bf16 ----------------
__global__ __launch_bounds__(256) void vtrans_kernel(const unsigned short* __restrict__ qkvb,
                                                     unsigned short* __restrict__ vtg) {
    __shared__ unsigned short t[64 * 66];
    const int tid = threadIdx.x;
    const int t0 = blockIdx.x * 64;
    const int bh = blockIdx.y;
    const int b = bh >> 4, h = bh & 15;
    const unsigned short* src = qkvb + (size_t)(b * 2048 + t0) * 3072 + 2048 + h * 64;
#pragma unroll
    for (int c = 0; c < 2; ++c) {
        int cid = c * 256 + tid;
        int row = cid >> 3, cc = cid & 7;
        *(int4*)&t[row * 66 + cc * 8] = *(const int4*)&src[(size_t)row * 3072 + cc * 8];
    }
    __syncthreads();
    unsigned short* dst = vtg + (size_t)bh * 64 * 2048 + t0;
#pragma unroll
    for (int c = 0; c < 2; ++c) {
        int cid = c * 256 + tid;
        int d = cid >> 3, cc2 = cid & 7;
        bf16x8 v;
#pragma unroll
        for (int j = 0; j < 8; ++j) v[j] = (short)t[(cc2 * 8 + j) * 66 + d];
        *(bf16x8*)&dst[(size_t)d * 2048 + cc2 * 8] = v;
    }
}

// ---------------- GEMM 256x256, BK=64, 8 waves (2Mx4N), R8/R11 4-phase schedule -----
template <int ACT, int OBF, int OBF2>
__global__ __launch_bounds__(512, 2) void gemm256_kernel(
    const unsigned short* __restrict__ A, const unsigned short* __restrict__ Bt,
    const float* __restrict__ bias, void* __restrict__ out, void* __restrict__ out2,
    int N, int Ktot, int gridNt, int GM, int nSlices) {
    __shared__ __align__(16) unsigned short lA[2][256 * 64];
    __shared__ __align__(16) unsigned short lB[2][256 * 64];
    const int tid = threadIdx.x;
    const int lane = tid & 63, wid = tid >> 6;
    const int g = lane >> 4, lr = lane & 15;
    const int wm = wid >> 2, wn = wid & 3;

    const int nwg = gridDim.x, cpx = nwg >> 3, bid = blockIdx.x;
    const int wkid = (bid & 7) * cpx + (bid >> 3);
    const int bps = nwg / nSlices;
    const int sl = wkid / bps, rem = wkid % bps;
    const int mt = (rem / (GM * gridNt)) * GM + (rem % GM);
    const int nt = (rem / GM) % gridNt;
    const int m0 = mt * 256, n0 = nt * 256;
    const int Ksl = Ktot / nSlices;
    const int kb0 = sl * Ksl;
    const int nkt = Ksl >> 6;
    void* outp = (sl == 0) ? out : out2;

    auto stageA = [&](int s, int kt, int bb) {  // s in [0,4): covers kb 2s..2s+1
        int c = s * 512 + tid;
        int row = c & 255, kb = c >> 8;
        gload16(&A[(size_t)(m0 + row) * Ktot + kb0 + kt * 64 + kb * 8],
                &lA[bb][(size_t)(s * 512 + (tid & ~63)) * 8]);
    };
    auto stageB = [&](int s, int kt, int bb) {
        int c = s * 512 + tid;
        int row = c & 255, kb = c >> 8;
        gload16(&Bt[(size_t)(n0 + row) * Ktot + kb0 + kt * 64 + kb * 8],
                &lB[bb][(size_t)(s * 512 + (tid & ~63)) * 8]);
    };

    f32x4 acc[8][4] = {};
    bf16x8 bfr[4];

    // prologue: tile 0 in group order {A01}{B01}{A23}{B23}
    stageA(0, 0, 0); stageA(1, 0, 0); stageB(0, 0, 0); stageB(1, 0, 0);
    stageA(2, 0, 0); stageA(3, 0, 0); stageB(2, 0, 0); stageB(3, 0, 0);
    asm volatile("s_waitcnt vmcnt(4)" ::: "memory");
    __builtin_amdgcn_s_barrier();
    asm volatile("" ::: "memory");

    for (int kt = 0; kt < nkt; ++kt) {
        const int buf = kt & 1;
        const bool more = (kt + 1 < nkt);
#pragma unroll
        for (int p = 0; p < 4; ++p) {
            const int ks = p >> 1, mh = p & 1;
            bf16x8 af[4];
#pragma unroll
            for (int mf2 = 0; mf2 < 4; ++mf2) {
                int c = (ks * 4 + g) * 256 + wm * 128 + (mh * 4 + mf2) * 16 + lr;
                af[mf2] = *(const bf16x8*)&lA[buf][(size_t)c * 8];
            }
            if (mh == 0) {
#pragma unroll
                for (int nf = 0; nf < 4; ++nf) {
                    int c = (ks * 4 + g) * 256 + wn * 64 + nf * 16 + lr;
                    bfr[nf] = *(const bf16x8*)&lB[buf][(size_t)c * 8];
                }
            }
            if (more) {
                if (p == 0)      { stageA(0, kt + 1, buf ^ 1); stageA(1, kt + 1, buf ^ 1); }
                else if (p == 1) { stageB(0, kt + 1, buf ^ 1); stageB(1, kt + 1, buf ^ 1); }
                else if (p == 2) { stageA(2, kt + 1, buf ^ 1); stageA(3, kt + 1, buf ^ 1); }
                else             { stageB(2, kt + 1, buf ^ 1); stageB(3, kt + 1, buf ^ 1); }
            }
            __builtin_amdgcn_s_barrier();
            asm volatile("s_waitcnt lgkmcnt(0)" ::: "memory");
            __builtin_amdgcn_sched_barrier(0);
            __builtin_amdgcn_s_setprio(1);
#pragma unroll
            for (int mf2 = 0; mf2 < 4; ++mf2)
#pragma unroll
                for (int nf = 0; nf < 4; ++nf)
                    acc[mh * 4 + mf2][nf] = __builtin_amdgcn_mfma_f32_16x16x32_bf16(
                        af[mf2], bfr[nf], acc[mh * 4 + mf2][nf], 0, 0, 0);
            __builtin_amdgcn_s_setprio(0);
            __builtin_amdgcn_sched_barrier(0);
            if (p == 1) {
                if (more) asm volatile("s_waitcnt vmcnt(4)" ::: "memory");
                else      asm volatile("s_waitcnt vmcnt(0)" ::: "memory");
            } else if (p == 3) {
                if (more) asm volatile("s_waitcnt vmcnt(4)" ::: "memory");
            }
            __builtin_amdgcn_s_barrier();
            asm volatile("" ::: "memory");
        }
    }

    // epilogue: bias (slice 0 only) + optional GELU, store
#pragma unroll
    for (int mf = 0; mf < 8; ++mf) {
#pragma unroll
        for (int nf = 0; nf < 4; ++nf) {
            int col = n0 + wn * 64 + nf * 16 + lr;
            float bv = (sl == 0) ? bias[col] : 0.0f;
#pragma unroll
            for (int r = 0; r < 4; ++r) {
                int row = m0 + wm * 128 + mf * 16 + g * 4 + r;
                float v = acc[mf][nf][r] + bv;
                if (ACT == 1) v = gelu_f(v);
                if (sl == 0) {
                    if (OBF)
                        ((unsigned short*)outp)[(size_t)row * N + col] = f2bf(v);
                    else
                        ((float*)outp)[(size_t)row * N + col] = v;
                } else {
                    if (OBF2)
                        ((unsigned short*)outp)[(size_t)row * N + col] = f2bf(v);
                    else
                        ((float*)outp)[(size_t)row * N + col] = v;
                }
            }
        }
    }
}

// -------- flash attention v5: QBLK=256 (8 waves), KVBLK=128, defer-max, XCD aff -----
// 256 blocks (4 pq x 16 h x 4 b), pairing J=7-p then J=p (18 tile-units/block).
// Per-wave compute path identical to v4; act0/act1 gating (R2 pattern) handles
// fully-masked (wave, tile) pairs created by the 256-row q-block.
__global__ __launch_bounds__(512, 2) void attn_kernel(const unsigned short* __restrict__ qkv,
                                                      const unsigned short* __restrict__ vtg,
                                                      unsigned short* __restrict__ y) {
    __shared__ unsigned short Kl[2][128 * 64];
    __shared__ unsigned short Vl[2][64 * 128];
    const int tid = threadIdx.x, lane = tid & 63, w = tid >> 6;
    const int g = lane >> 4, lr = lane & 15;
    const int id = blockIdx.x + 4 * (blockIdx.y + 16 * blockIdx.z);
    const int xcd = id & 7, wrk = id >> 3;
    const int bh = xcd * 8 + (wrk & 7);
    const int p = wrk >> 3;  // 0..3
    const int b = bh >> 4, h = bh & 15;
    const size_t rs3 = 3072;
    const unsigned short* qbase = qkv + (size_t)b * 2048 * rs3 + h * 64;
    const unsigned short* kbase = qbase + 1024;
    const unsigned short* vbase = vtg + (size_t)bh * 64 * 2048;

    // staging offsets (512 threads, 2 K-loads + 2 V-loads each per tile)
    int ksoff[2], vsoff[2], ldoff[2];
#pragma unroll
    for (int c = 0; c < 2; ++c) {
        int cid = c * 512 + tid;
        int krow = cid >> 3, kcc = cid & 7;
        ksoff[c] = krow * 3072 + (kcc ^ (krow & 7) ^ ((krow >> 3) & 7)) * 8;
        int d = cid >> 4, tcs = cid & 15;
        vsoff[c] = d * 2048 + (tcs ^ ((d & 7) ^ ((d >> 3) & 7))) * 8;
        ldoff[c] = (c * 512 + (tid & ~63)) * 8;
    }

    const int idxP0 = 4 * (32 * (g & 1) + lr);
    const int idxP1 = idxP0 + 64;
    int idxA[4];
#pragma unroll
    for (int r = 0; r < 4; ++r) idxA[r] = 4 * (g * 20 + r);
    const bool ghigh = (g >> 1) != 0;
    const float qscale = 0.125f * 1.44269504089f;

    auto process = [&](int J) {
        const int q0w = J * 256 + w * 32;
        const int ktend = 2 * J + 2;
#pragma unroll
        for (int c = 0; c < 2; ++c) {
            gload16(&kbase[ksoff[c]], &Kl[0][ldoff[c]]);
            gload16(&vbase[vsoff[c]], &Vl[0][ldoff[c]]);
        }
        int qf[2][2][4];
#pragma unroll
        for (int sub = 0; sub < 2; ++sub)
#pragma unroll
            for (int f = 0; f < 2; ++f) {
                int4 v = *(const int4*)&qbase[(size_t)(q0w + sub * 16 + lr) * rs3 + f * 32 + g * 8];
                int vv[4] = {v.x, v.y, v.z, v.w};
#pragma unroll
                for (int i = 0; i < 4; ++i) {
                    unsigned int u = (unsigned int)vv[i];
                    float lo = __builtin_bit_cast(float, u << 16) * qscale;
                    float hi = __builtin_bit_cast(float, u & 0xffff0000u) * qscale;
                    qf[sub][f][i] = cvtpk_bf16(lo, hi);
                }
            }

        f32x4 O[2][4] = {};
        float m_[2] = {-3.0e38f, -3.0e38f}, l_[2] = {0.f, 0.f};

        int buf = 0;
        for (int kt = 0; kt < ktend; ++kt) {
            asm volatile("s_waitcnt vmcnt(0)" ::: "memory");
            __builtin_amdgcn_s_barrier();
            asm volatile("" ::: "memory");
            if (kt + 1 < ktend) {
#pragma unroll
                for (int c = 0; c < 2; ++c) {
                    gload16(&kbase[(size_t)(kt + 1) * 128 * 3072 + ksoff[c]], &Kl[buf ^ 1][ldoff[c]]);
                    gload16(&vbase[vsoff[c] + (kt + 1) * 128], &Vl[buf ^ 1][ldoff[c]]);
                }
            }
            const unsigned short* Kc = Kl[buf];
            const unsigned short* Vc = Vl[buf];

            const bool act0 = (kt * 128) <= (q0w + 15);
            const bool act1 = (kt * 128) <= (q0w + 31);
            if (!act0 && !act1) { buf ^= 1; continue; }

            f32x4 s0[8], s1[8];
#pragma unroll
            for (int st = 0; st < 8; ++st) {
                int rbase = (st * 16 + lr) * 64;
                int sw = (lr & 7) ^ ((st * 2 + (lr >> 3)) & 7);
                bf16x8 kf0 = *(const bf16x8*)&Kc[rbase + ((g ^ sw) * 8)];
                bf16x8 kf1 = *(const bf16x8*)&Kc[rbase + (((4 + g) ^ sw) * 8)];
                if (act0) {
                    f32x4 a = {};
                    a = __builtin_amdgcn_mfma_f32_16x16x32_bf16(kf0, *(const bf16x8*)&qf[0][0], a, 0, 0, 0);
                    a = __builtin_amdgcn_mfma_f32_16x16x32_bf16(kf1, *(const bf16x8*)&qf[0][1], a, 0, 0, 0);
                    s0[st] = a;
                }
                if (act1) {
                    f32x4 c = {};
                    c = __builtin_amdgcn_mfma_f32_16x16x32_bf16(kf0, *(const bf16x8*)&qf[1][0], c, 0, 0, 0);
                    c = __builtin_amdgcn_mfma_f32_16x16x32_bf16(kf1, *(const bf16x8*)&qf[1][1], c, 0, 0, 0);
                    s1[st] = c;
                }
            }

            int wt0[4][4], wt1[4][4];
#pragma unroll
            for (int sub = 0; sub < 2; ++sub) {
                if (sub == 0 && !act0) continue;
                if (sub == 1 && !act1) continue;
                f32x4* s = (sub == 0) ? s0 : s1;
                const int qmin = q0w + sub * 16;
                if (kt * 128 + 127 > qmin) {  // diagonal-overlap: causal mask
                    int qv = qmin + lr;
#pragma unroll
                    for (int st = 0; st < 8; ++st) {
                        int keyb = kt * 128 + st * 16 + g * 4;
#pragma unroll
                        for (int r = 0; r < 4; ++r)
                            if (keyb + r > qv) s[st][r] = -3.0e38f;
                    }
                }
                float mx = fmaxf(fmaxf(s[0][0], s[0][1]), fmaxf(s[0][2], s[0][3]));
#pragma unroll
                for (int st = 1; st < 8; ++st)
                    mx = fmaxf(mx, fmaxf(fmaxf(s[st][0], s[st][1]), fmaxf(s[st][2], s[st][3])));
                mx = fmaxf(mx, __shfl_xor(mx, 16));
                mx = fmaxf(mx, __shfl_xor(mx, 32));
                if (__any(mx - m_[sub] > 11.5f)) {
                    float mnew = fmaxf(m_[sub], mx);
                    float alpha = __builtin_amdgcn_exp2f(m_[sub] - mnew);
                    m_[sub] = mnew;
                    l_[sub] *= alpha;
                    int av = __builtin_bit_cast(int, alpha);
                    f32x4* Os = O[sub];
#pragma unroll
                    for (int r = 0; r < 4; ++r) {
                        float ar = __builtin_bit_cast(float, __builtin_amdgcn_ds_bpermute(idxA[r], av));
#pragma unroll
                        for (int dt = 0; dt < 4; ++dt) Os[dt][r] *= ar;
                    }
                }
                float rs = 0.f;
#pragma unroll
                for (int st = 0; st < 8; ++st)
#pragma unroll
                    for (int r = 0; r < 4; ++r) {
                        float pp = __builtin_amdgcn_exp2f(s[st][r] - m_[sub]);
                        s[st][r] = pp;
                        rs += pp;
                    }
                rs += __shfl_xor(rs, 16);
                rs += __shfl_xor(rs, 32);
                l_[sub] += rs;
                int ws_[8][2];
#pragma unroll
                for (int st = 0; st < 8; ++st) {
                    ws_[st][0] = cvtpk_bf16(s[st][0], s[st][1]);
                    ws_[st][1] = cvtpk_bf16(s[st][2], s[st][3]);
                }
                int(*wt)[4] = (sub == 0) ? wt0 : wt1;
#pragma unroll
                for (int ks = 0; ks < 4; ++ks)
#pragma unroll
                    for (int hp = 0; hp < 4; ++hp) {
                        int idx = (hp < 2) ? idxP0 : idxP1;
                        int v0 = __builtin_amdgcn_ds_bpermute(idx, ws_[2 * ks][hp & 1]);
                        int v1 = __builtin_amdgcn_ds_bpermute(idx, ws_[2 * ks + 1][hp & 1]);
                        wt[ks][hp] = ghigh ? v1 : v0;
                    }
            }

#pragma unroll
            for (int ks = 0; ks < 4; ++ks) {
                bf16x8 pa0 = *(const bf16x8*)&wt0[ks][0];
                bf16x8 pa1 = *(const bf16x8*)&wt1[ks][0];
#pragma unroll
                for (int dt = 0; dt < 4; ++dt) {
                    int d = dt * 16 + lr;
                    int tc = (ks * 4 + g) ^ ((lr & 7) ^ ((dt * 2 + (lr >> 3)) & 7));
                    bf16x8 vf = *(const bf16x8*)&Vc[d * 128 + tc * 8];
                    if (act0) O[0][dt] = __builtin_amdgcn_mfma_f32_16x16x32_bf16(pa0, vf, O[0][dt], 0, 0, 0);
                    if (act1) O[1][dt] = __builtin_amdgcn_mfma_f32_16x16x32_bf16(pa1, vf, O[1][dt], 0, 0, 0);
                }
            }
            buf ^= 1;
        }

#pragma unroll
        for (int sub = 0; sub < 2; ++sub) {
            int lv = __builtin_bit_cast(int, l_[sub]);
#pragma unroll
            for (int r = 0; r < 4; ++r) {
                float lval = __builtin_bit_cast(float, __builtin_amdgcn_ds_bpermute(idxA[r], lv));
                float inv = __builtin_amdgcn_rcpf(lval);
                int q = q0w + sub * 16 + g * 4 + r;
#pragma unroll
                for (int dt = 0; dt < 4; ++dt)
                    y[(size_t)(b * 2048 + q) * 1024 + h * 64 + dt * 16 + lr] =
                        f2bf(O[sub][dt][r] * inv);
            }
        }
    };

    process(7 - p);
    __syncthreads();
    process(p);
}

// ------ residual + layernorm: out = base + LN(d1 + d2)*g+b; d1,d2 bf16 ------
// base f32 (BASEBF=0) or bf16 (BASEBF=1)
template <int WRITE_BF, int BASEBF>
__global__ __launch_bounds__(256) void ln_kernel(const void* __restrict__ base,
                                                 const unsigned short* __restrict__ d1,
                                                 const unsigned short* __restrict__ d2,
                                                 const float* __restrict__ gw,
                                                 const float* __restrict__ bw,
                                                 float* __restrict__ outf,
                                                 unsigned short* __restrict__ outb) {
    const int row = blockIdx.x;
    const int tid = threadIdx.x;
    ushort4 u1 = *(const ushort4*)&d1[(size_t)row * 1024 + tid * 4];
    ushort4 u2 = *(const ushort4*)&d2[(size_t)row * 1024 + tid * 4];
    float4 x;
    x.x = bf2f(u1.x) + bf2f(u2.x);
    x.y = bf2f(u1.y) + bf2f(u2.y);
    x.z = bf2f(u1.z) + bf2f(u2.z);
    x.w = bf2f(u1.w) + bf2f(u2.w);
    float s = x.x + x.y + x.z + x.w;
    float s2 = x.x * x.x + x.y * x.y + x.z * x.z + x.w * x.w;
#pragma unroll
    for (int off = 1; off < 64; off <<= 1) {
        s += __shfl_xor(s, off);
        s2 += __shfl_xor(s2, off);
    }
    __shared__ float red[8];
    if ((tid & 63) == 0) {
        red[tid >> 6] = s;
        red[4 + (tid >> 6)] = s2;
    }
    __syncthreads();
    s = red[0] + red[1] + red[2] + red[3];
    s2 = red[4] + red[5] + red[6] + red[7];
    float mu = s * (1.f / 1024.f);
    float var = s2 * (1.f / 1024.f) - mu * mu;
    float rsig = rsqrtf(var + 1e-5f);
    float4 bb;
    if (BASEBF) {
        const unsigned short* bs = (const unsigned short*)base + (size_t)row * 1024 + tid * 4;
        ushort4 u = *(const ushort4*)bs;
        bb.x = bf2f(u.x); bb.y = bf2f(u.y); bb.z = bf2f(u.z); bb.w = bf2f(u.w);
    } else {
        bb = *(const float4*)((const float*)base + (size_t)row * 1024 + tid * 4);
    }
    float4 gv = *(const float4*)&gw[tid * 4];
    float4 bv = *(const float4*)&bw[tid * 4];
    float4 o;
    o.x = bb.x + (x.x - mu) * rsig * gv.x + bv.x;
    o.y = bb.y + (x.y - mu) * rsig * gv.y + bv.y;
    o.z = bb.z + (x.z - mu) * rsig * gv.z + bv.z;
    o.w = bb.w + (x.w - mu) * rsig * gv.w + bv.w;
    if (outf) *(float4*)&outf[(size_t)row * 1024 + tid * 4] = o;
    if (WRITE_BF) {
        unsigned short* ob = outb + (size_t)row * 1024 + tid * 4;
        ob[0] = f2bf(o.x);
        ob[1] = f2bf(o.y);
        ob[2] = f2bf(o.z);
        ob[3] = f2bf(o.w);
    }
}

extern "C" void kernel_launch(void* const* d_in, const int* in_sizes, int n_in,
                              void* d_out, int out_size, void* d_ws, size_t ws_size,
                              hipStream_t stream) {
    const float* x = (const float*)d_in[0];
    const float* w_qkv = (const float*)d_in[1];
    const float* b_qkv = (const float*)d_in[2];
    const float* w_out = (const float*)d_in[3];
    const float* b_out = (const float*)d_in[4];
    const float* w1 = (const float*)d_in[5];
    const float* b1 = (const float*)d_in[6];
    const float* w2 = (const float*)d_in[7];
    const float* b2 = (const float*)d_in[8];
    const float* g1 = (const float*)d_in[9];
    const float* be1 = (const float*)d_in[10];
    const float* g2 = (const float*)d_in[11];
    const float* be2 = (const float*)d_in[12];

    const size_t MB = 1ull << 20;
    if (ws_size < 184 * MB) return;
    char* ws = (char*)d_ws;
    // live-range-checked layout (all inter-kernel activations bf16):
    unsigned short* xb    = (unsigned short*)(ws + 0);         // 0-16   cvt -> qkv
    unsigned short* vtg   = (unsigned short*)(ws + 0);         // 0-16   vtrans -> attn
    unsigned short* attnp1= (unsigned short*)(ws + 0);         // 0-16   outproj -> ln1 (bf16)
    unsigned short* hb    = (unsigned short*)(ws + 0);         // 0-64   mlp1 -> mlp2 (after ln1)
    unsigned short* wqkvt = (unsigned short*)(ws + 16 * MB);   // 16-22  -> qkv
    unsigned short* qkvb  = (unsigned short*)(ws + 22 * MB);   // 22-70  qkv -> attn
    unsigned short* woutt = (unsigned short*)(ws + 70 * MB);   // 70-72  -> outproj
    unsigned short* yb    = (unsigned short*)(ws + 72 * MB);   // 72-88  attn -> outproj
    unsigned short* ff1b  = (unsigned short*)(ws + 72 * MB);   // 72-88  mlp2 -> ln2 (bf16)
    unsigned short* attnp = (unsigned short*)(ws + 88 * MB);   // 88-104 outproj -> ln1 (bf16)
    unsigned short* ffb   = (unsigned short*)(ws + 88 * MB);   // 88-104 mlp2 -> ln2 (bf16)
    unsigned short* x2b   = (unsigned short*)(ws + 152 * MB);  // 152-168 ln1 -> mlp1, ln2
    unsigned short* w1t   = (unsigned short*)(ws + 168 * MB);  // 168-176 -> mlp1
    unsigned short* w2t   = (unsigned short*)(ws + 176 * MB);  // 176-184 -> mlp2

    // prep
    cvtbf_kernel<<<8192, 256, 0, stream>>>(x, xb);
    transpose_cvt_kernel<<<dim3(96, 32), dim3(32, 8), 0, stream>>>(w_qkv, wqkvt, 1024, 3072);
    transpose_cvt_kernel<<<dim3(32, 32), dim3(32, 8), 0, stream>>>(w_out, woutt, 1024, 1024);
    transpose_cvt_kernel<<<dim3(128, 32), dim3(32, 8), 0, stream>>>(w1, w1t, 1024, 4096);
    transpose_cvt_kernel<<<dim3(32, 128), dim3(32, 8), 0, stream>>>(w2, w2t, 4096, 1024);
    // qkv = x @ w_qkv + b_qkv (bf16) [8192x3072, K=1024]: 32mt x 12nt, GM=4
    gemm256_kernel<0, 1, 1><<<384, 512, 0, stream>>>(xb, wqkvt, b_qkv, qkvb, nullptr,
                                                     3072, 1024, 12, 4, 1);
    // V^T pre-transpose
    vtrans_kernel<<<dim3(32, 64), 256, 0, stream>>>(qkvb, vtg);
    // attention (QBLK=256, 8 waves)
    attn_kernel<<<dim3(4, 16, 4), 512, 0, stream>>>(qkvb, vtg, yb);
    // out proj (bf16 + bf16 partial, split-K=2) [8192x1024, K=1024]: 2sl x 32mt x 4nt, GM=8
    gemm256_kernel<0, 1, 1><<<256, 512, 0, stream>>>(yb, woutt, b_out, attnp, attnp1,
                                                     1024, 1024, 4, 8, 2);
    // x2b = bf16(x + LN(attnp + attnp1))
    ln_kernel<1, 0><<<8192, 256, 0, stream>>>(x, attnp, attnp1, g1, be1, nullptr, x2b);
    // h = gelu(x2 @ w1 + b1) (bf16) [8192x4096, K=1024]: 32mt x 16nt, GM=4
    gemm256_kernel<1, 1, 1><<<512, 512, 0, stream>>>(x2b, w1t, b1, hb, nullptr,
                                                     4096, 1024, 16, 4, 1);
    // f = h @ w2 + b2 (bf16 + bf16 partial, split-K=2) [8192x1024, K=4096]: 2sl x 32mt x 4nt, GM=8
    gemm256_kernel<0, 1, 1><<<256, 512, 0, stream>>>(hb, w2t, b2, ffb, ff1b,
                                                     1024, 4096, 4, 8, 2);
    // out = x2b + LN(ffb + ff1b)   (f32 out)
    ln_kernel<0, 1><<<8192, 256, 0, stream>>>(x2b, ffb, ff1b, g2, be2, (float*)d_out, nullptr);
}

// Round 18
// 444.973 us; speedup vs baseline: 1.0206x; 1.0206x over previous
//
#include <hip/hip_runtime.h>
#include <hip/hip_bf16.h>

typedef unsigned short ushort_t;
using bf16x8 = __attribute__((ext_vector_type(8))) short;
using f32x4  = __attribute__((ext_vector_type(4))) float;

#define DEV __device__ __forceinline__

DEV unsigned short f2bf(float f) {
    unsigned int u = __builtin_bit_cast(unsigned int, f);
    u = (u + 0x7fffu + ((u >> 16) & 1u)) >> 16;
    return (unsigned short)u;
}

DEV float bf2f(unsigned short s) {
    return __builtin_bit_cast(float, (unsigned int)s << 16);
}

DEV int cvtpk_bf16(float lo, float hi) {
    int r;
    asm("v_cvt_pk_bf16_f32 %0, %1, %2" : "=v"(r) : "v"(lo), "v"(hi));
    return r;
}

DEV void gload16(const unsigned short* g, unsigned short* l) {
    __builtin_amdgcn_global_load_lds(
        (const __attribute__((address_space(1))) void*)g,
        (__attribute__((address_space(3))) void*)l, 16, 0, 0);
}

// sigmoid-form GELU: v*sigmoid(1.702v); max err ~0.02 abs (threshold 0.18)
DEV float gelu_f(float v) {
    float t = __builtin_amdgcn_exp2f(v * 2.4554946f);
    return v * t * __builtin_amdgcn_rcpf(t + 1.0f);
}

// ---------------- f32 -> bf16 convert ----------------
__global__ __launch_bounds__(256) void cvtbf_kernel(const float* __restrict__ in,
                                                    unsigned short* __restrict__ out) {
    int i = (blockIdx.x * 256 + threadIdx.x) * 4;
    float4 v = *(const float4*)&in[i];
    out[i + 0] = f2bf(v.x);
    out[i + 1] = f2bf(v.y);
    out[i + 2] = f2bf(v.z);
    out[i + 3] = f2bf(v.w);
}

// ---------------- transpose + convert: in[R,C] f32 -> out[C,R] bf16 ----------------
__global__ __launch_bounds__(256) void transpose_cvt_kernel(const float* __restrict__ in,
                                                            unsigned short* __restrict__ out,
                                                            int R, int C) {
    __shared__ float t[32][33];
    int tx = threadIdx.x, ty = threadIdx.y;
    int c0 = blockIdx.x * 32, r0 = blockIdx.y * 32;
#pragma unroll
    for (int i = 0; i < 4; ++i)
        t[ty + i * 8][tx] = in[(size_t)(r0 + ty + i * 8) * C + c0 + tx];
    __syncthreads();
#pragma unroll
    for (int i = 0; i < 4; ++i)
        out[(size_t)(c0 + ty + i * 8) * R + r0 + tx] = f2bf(t[tx][ty + i * 8]);
}

// ---------------- V transpose: qkvb V-part -> vtg[bh][64][2048] bf16 ----------------
__global__ __launch_bounds__(256) void vtrans_kernel(const unsigned short* __restrict__ qkvb,
                                                     unsigned short* __restrict__ vtg) {
    __shared__ unsigned short t[64 * 66];
    const int tid = threadIdx.x;
    const int t0 = blockIdx.x * 64;
    const int bh = blockIdx.y;
    const int b = bh >> 4, h = bh & 15;
    const unsigned short* src = qkvb + (size_t)(b * 2048 + t0) * 3072 + 2048 + h * 64;
#pragma unroll
    for (int c = 0; c < 2; ++c) {
        int cid = c * 256 + tid;
        int row = cid >> 3, cc = cid & 7;
        *(int4*)&t[row * 66 + cc * 8] = *(const int4*)&src[(size_t)row * 3072 + cc * 8];
    }
    __syncthreads();
    unsigned short* dst = vtg + (size_t)bh * 64 * 2048 + t0;
#pragma unroll
    for (int c = 0; c < 2; ++c) {
        int cid = c * 256 + tid;
        int d = cid >> 3, cc2 = cid & 7;
        bf16x8 v;
#pragma unroll
        for (int j = 0; j < 8; ++j) v[j] = (short)t[(cc2 * 8 + j) * 66 + d];
        *(bf16x8*)&dst[(size_t)d * 2048 + cc2 * 8] = v;
    }
}

// ---------------- GEMM 256x256, BK=64, 8 waves (2Mx4N), R8/R11 4-phase schedule -----
template <int ACT, int OBF, int OBF2>
__global__ __launch_bounds__(512, 2) void gemm256_kernel(
    const unsigned short* __restrict__ A, const unsigned short* __restrict__ Bt,
    const float* __restrict__ bias, void* __restrict__ out, void* __restrict__ out2,
    int N, int Ktot, int gridNt, int GM, int nSlices) {
    __shared__ __align__(16) unsigned short lA[2][256 * 64];
    __shared__ __align__(16) unsigned short lB[2][256 * 64];
    const int tid = threadIdx.x;
    const int lane = tid & 63, wid = tid >> 6;
    const int g = lane >> 4, lr = lane & 15;
    const int wm = wid >> 2, wn = wid & 3;

    const int nwg = gridDim.x, cpx = nwg >> 3, bid = blockIdx.x;
    const int wkid = (bid & 7) * cpx + (bid >> 3);
    const int bps = nwg / nSlices;
    const int sl = wkid / bps, rem = wkid % bps;
    const int mt = (rem / (GM * gridNt)) * GM + (rem % GM);
    const int nt = (rem / GM) % gridNt;
    const int m0 = mt * 256, n0 = nt * 256;
    const int Ksl = Ktot / nSlices;
    const int kb0 = sl * Ksl;
    const int nkt = Ksl >> 6;
    void* outp = (sl == 0) ? out : out2;

    auto stageA = [&](int s, int kt, int bb) {  // s in [0,4): covers kb 2s..2s+1
        int c = s * 512 + tid;
        int row = c & 255, kb = c >> 8;
        gload16(&A[(size_t)(m0 + row) * Ktot + kb0 + kt * 64 + kb * 8],
                &lA[bb][(size_t)(s * 512 + (tid & ~63)) * 8]);
    };
    auto stageB = [&](int s, int kt, int bb) {
        int c = s * 512 + tid;
        int row = c & 255, kb = c >> 8;
        gload16(&Bt[(size_t)(n0 + row) * Ktot + kb0 + kt * 64 + kb * 8],
                &lB[bb][(size_t)(s * 512 + (tid & ~63)) * 8]);
    };

    f32x4 acc[8][4] = {};
    bf16x8 bfr[4];

    // prologue: tile 0 in group order {A01}{B01}{A23}{B23}
    stageA(0, 0, 0); stageA(1, 0, 0); stageB(0, 0, 0); stageB(1, 0, 0);
    stageA(2, 0, 0); stageA(3, 0, 0); stageB(2, 0, 0); stageB(3, 0, 0);
    asm volatile("s_waitcnt vmcnt(4)" ::: "memory");
    __builtin_amdgcn_s_barrier();
    asm volatile("" ::: "memory");

    for (int kt = 0; kt < nkt; ++kt) {
        const int buf = kt & 1;
        const bool more = (kt + 1 < nkt);
#pragma unroll
        for (int p = 0; p < 4; ++p) {
            const int ks = p >> 1, mh = p & 1;
            bf16x8 af[4];
#pragma unroll
            for (int mf2 = 0; mf2 < 4; ++mf2) {
                int c = (ks * 4 + g) * 256 + wm * 128 + (mh * 4 + mf2) * 16 + lr;
                af[mf2] = *(const bf16x8*)&lA[buf][(size_t)c * 8];
            }
            if (mh == 0) {
#pragma unroll
                for (int nf = 0; nf < 4; ++nf) {
                    int c = (ks * 4 + g) * 256 + wn * 64 + nf * 16 + lr;
                    bfr[nf] = *(const bf16x8*)&lB[buf][(size_t)c * 8];
                }
            }
            if (more) {
                if (p == 0)      { stageA(0, kt + 1, buf ^ 1); stageA(1, kt + 1, buf ^ 1); }
                else if (p == 1) { stageB(0, kt + 1, buf ^ 1); stageB(1, kt + 1, buf ^ 1); }
                else if (p == 2) { stageA(2, kt + 1, buf ^ 1); stageA(3, kt + 1, buf ^ 1); }
                else             { stageB(2, kt + 1, buf ^ 1); stageB(3, kt + 1, buf ^ 1); }
            }
            __builtin_amdgcn_s_barrier();
            asm volatile("s_waitcnt lgkmcnt(0)" ::: "memory");
            __builtin_amdgcn_sched_barrier(0);
            __builtin_amdgcn_s_setprio(1);
#pragma unroll
            for (int mf2 = 0; mf2 < 4; ++mf2)
#pragma unroll
                for (int nf = 0; nf < 4; ++nf)
                    acc[mh * 4 + mf2][nf] = __builtin_amdgcn_mfma_f32_16x16x32_bf16(
                        af[mf2], bfr[nf], acc[mh * 4 + mf2][nf], 0, 0, 0);
            __builtin_amdgcn_s_setprio(0);
            __builtin_amdgcn_sched_barrier(0);
            if (p == 1) {
                if (more) asm volatile("s_waitcnt vmcnt(4)" ::: "memory");
                else      asm volatile("s_waitcnt vmcnt(0)" ::: "memory");
            } else if (p == 3) {
                if (more) asm volatile("s_waitcnt vmcnt(4)" ::: "memory");
            }
            __builtin_amdgcn_s_barrier();
            asm volatile("" ::: "memory");
        }
    }

    // epilogue: bias (slice 0 only) + optional GELU, store
#pragma unroll
    for (int mf = 0; mf < 8; ++mf) {
#pragma unroll
        for (int nf = 0; nf < 4; ++nf) {
            int col = n0 + wn * 64 + nf * 16 + lr;
            float bv = (sl == 0) ? bias[col] : 0.0f;
#pragma unroll
            for (int r = 0; r < 4; ++r) {
                int row = m0 + wm * 128 + mf * 16 + g * 4 + r;
                float v = acc[mf][nf][r] + bv;
                if (ACT == 1) v = gelu_f(v);
                if (sl == 0) {
                    if (OBF)
                        ((unsigned short*)outp)[(size_t)row * N + col] = f2bf(v);
                    else
                        ((float*)outp)[(size_t)row * N + col] = v;
                } else {
                    if (OBF2)
                        ((unsigned short*)outp)[(size_t)row * N + col] = f2bf(v);
                    else
                        ((float*)outp)[(size_t)row * N + col] = v;
                }
            }
        }
    }
}

// ---------------- flash attention v4: KVBLK=128, defer-max, bh->XCD affinity --------
__global__ __launch_bounds__(256, 2) void attn_kernel(const unsigned short* __restrict__ qkv,
                                                      const unsigned short* __restrict__ vtg,
                                                      unsigned short* __restrict__ y) {
    __shared__ unsigned short Kl[2][128 * 64];
    __shared__ unsigned short Vl[2][64 * 128];
    const int tid = threadIdx.x, lane = tid & 63, w = tid >> 6;
    const int g = lane >> 4, lr = lane & 15;
    const int id = blockIdx.x + 8 * (blockIdx.y + 16 * blockIdx.z);
    const int xcd = id & 7, wrk = id >> 3;
    const int bh = xcd * 8 + (wrk & 7);
    const int p = wrk >> 3;
    const int b = bh >> 4, h = bh & 15;
    const size_t rs3 = 3072;
    const unsigned short* qbase = qkv + (size_t)b * 2048 * rs3 + h * 64;
    const unsigned short* kbase = qbase + 1024;
    const unsigned short* vbase = vtg + (size_t)bh * 64 * 2048;

    int ksoff[4], vsoff[4], ldoff[4];
#pragma unroll
    for (int c = 0; c < 4; ++c) {
        int cid = c * 256 + tid;
        int krow = cid >> 3, kcc = cid & 7;
        ksoff[c] = krow * 3072 + (kcc ^ (krow & 7) ^ ((krow >> 3) & 7)) * 8;
        int d = cid >> 4, tcs = cid & 15;
        vsoff[c] = d * 2048 + (tcs ^ ((d & 7) ^ ((d >> 3) & 7))) * 8;
        ldoff[c] = (c * 256 + (tid & ~63)) * 8;
    }

    const int idxP0 = 4 * (32 * (g & 1) + lr);
    const int idxP1 = idxP0 + 64;
    int idxA[4];
#pragma unroll
    for (int r = 0; r < 4; ++r) idxA[r] = 4 * (g * 20 + r);
    const bool ghigh = (g >> 1) != 0;
    const float qscale = 0.125f * 1.44269504089f;

    auto process = [&](int J) {
        const int q0w = J * 128 + w * 32;
        const int ktend = J + 1;
#pragma unroll
        for (int c = 0; c < 4; ++c) {
            gload16(&kbase[ksoff[c]], &Kl[0][ldoff[c]]);
            gload16(&vbase[vsoff[c]], &Vl[0][ldoff[c]]);
        }
        int qf[2][2][4];
#pragma unroll
        for (int sub = 0; sub < 2; ++sub)
#pragma unroll
            for (int f = 0; f < 2; ++f) {
                int4 v = *(const int4*)&qbase[(size_t)(q0w + sub * 16 + lr) * rs3 + f * 32 + g * 8];
                int vv[4] = {v.x, v.y, v.z, v.w};
#pragma unroll
                for (int i = 0; i < 4; ++i) {
                    unsigned int u = (unsigned int)vv[i];
                    float lo = __builtin_bit_cast(float, u << 16) * qscale;
                    float hi = __builtin_bit_cast(float, u & 0xffff0000u) * qscale;
                    qf[sub][f][i] = cvtpk_bf16(lo, hi);
                }
            }

        f32x4 O[2][4] = {};
        float m_[2] = {-3.0e38f, -3.0e38f}, l_[2] = {0.f, 0.f};

        int buf = 0;
        for (int kt = 0; kt < ktend; ++kt) {
            asm volatile("s_waitcnt vmcnt(0)" ::: "memory");
            __builtin_amdgcn_s_barrier();
            asm volatile("" ::: "memory");
            if (kt + 1 < ktend) {
#pragma unroll
                for (int c = 0; c < 4; ++c) {
                    gload16(&kbase[(size_t)(kt + 1) * 128 * 3072 + ksoff[c]], &Kl[buf ^ 1][ldoff[c]]);
                    gload16(&vbase[vsoff[c] + (kt + 1) * 128], &Vl[buf ^ 1][ldoff[c]]);
                }
            }
            const unsigned short* Kc = Kl[buf];
            const unsigned short* Vc = Vl[buf];

            f32x4 s0[8], s1[8];
#pragma unroll
            for (int st = 0; st < 8; ++st) {
                int rbase = (st * 16 + lr) * 64;
                int sw = (lr & 7) ^ ((st * 2 + (lr >> 3)) & 7);
                bf16x8 kf0 = *(const bf16x8*)&Kc[rbase + ((g ^ sw) * 8)];
                bf16x8 kf1 = *(const bf16x8*)&Kc[rbase + (((4 + g) ^ sw) * 8)];
                f32x4 a = {};
                a = __builtin_amdgcn_mfma_f32_16x16x32_bf16(kf0, *(const bf16x8*)&qf[0][0], a, 0, 0, 0);
                a = __builtin_amdgcn_mfma_f32_16x16x32_bf16(kf1, *(const bf16x8*)&qf[0][1], a, 0, 0, 0);
                s0[st] = a;
                f32x4 c = {};
                c = __builtin_amdgcn_mfma_f32_16x16x32_bf16(kf0, *(const bf16x8*)&qf[1][0], c, 0, 0, 0);
                c = __builtin_amdgcn_mfma_f32_16x16x32_bf16(kf1, *(const bf16x8*)&qf[1][1], c, 0, 0, 0);
                s1[st] = c;
            }

            int wt0[4][4], wt1[4][4];
#pragma unroll
            for (int sub = 0; sub < 2; ++sub) {
                f32x4* s = (sub == 0) ? s0 : s1;
                const int qmin = q0w + sub * 16;
                if (kt == J) {
                    int qv = qmin + lr;
#pragma unroll
                    for (int st = 0; st < 8; ++st) {
                        int keyb = kt * 128 + st * 16 + g * 4;
#pragma unroll
                        for (int r = 0; r < 4; ++r)
                            if (keyb + r > qv) s[st][r] = -3.0e38f;
                    }
                }
                float mx = fmaxf(fmaxf(s[0][0], s[0][1]), fmaxf(s[0][2], s[0][3]));
#pragma unroll
                for (int st = 1; st < 8; ++st)
                    mx = fmaxf(mx, fmaxf(fmaxf(s[st][0], s[st][1]), fmaxf(s[st][2], s[st][3])));
                mx = fmaxf(mx, __shfl_xor(mx, 16));
                mx = fmaxf(mx, __shfl_xor(mx, 32));
                if (__any(mx - m_[sub] > 11.5f)) {
                    float mnew = fmaxf(m_[sub], mx);
                    float alpha = __builtin_amdgcn_exp2f(m_[sub] - mnew);
                    m_[sub] = mnew;
                    l_[sub] *= alpha;
                    int av = __builtin_bit_cast(int, alpha);
                    f32x4* Os = O[sub];
#pragma unroll
                    for (int r = 0; r < 4; ++r) {
                        float ar = __builtin_bit_cast(float, __builtin_amdgcn_ds_bpermute(idxA[r], av));
#pragma unroll
                        for (int dt = 0; dt < 4; ++dt) Os[dt][r] *= ar;
                    }
                }
                float rs = 0.f;
#pragma unroll
                for (int st = 0; st < 8; ++st)
#pragma unroll
                    for (int r = 0; r < 4; ++r) {
                        float pp = __builtin_amdgcn_exp2f(s[st][r] - m_[sub]);
                        s[st][r] = pp;
                        rs += pp;
                    }
                rs += __shfl_xor(rs, 16);
                rs += __shfl_xor(rs, 32);
                l_[sub] += rs;
                int ws_[8][2];
#pragma unroll
                for (int st = 0; st < 8; ++st) {
                    ws_[st][0] = cvtpk_bf16(s[st][0], s[st][1]);
                    ws_[st][1] = cvtpk_bf16(s[st][2], s[st][3]);
                }
                int(*wt)[4] = (sub == 0) ? wt0 : wt1;
#pragma unroll
                for (int ks = 0; ks < 4; ++ks)
#pragma unroll
                    for (int hp = 0; hp < 4; ++hp) {
                        int idx = (hp < 2) ? idxP0 : idxP1;
                        int v0 = __builtin_amdgcn_ds_bpermute(idx, ws_[2 * ks][hp & 1]);
                        int v1 = __builtin_amdgcn_ds_bpermute(idx, ws_[2 * ks + 1][hp & 1]);
                        wt[ks][hp] = ghigh ? v1 : v0;
                    }
            }

#pragma unroll
            for (int ks = 0; ks < 4; ++ks) {
                bf16x8 pa0 = *(const bf16x8*)&wt0[ks][0];
                bf16x8 pa1 = *(const bf16x8*)&wt1[ks][0];
#pragma unroll
                for (int dt = 0; dt < 4; ++dt) {
                    int d = dt * 16 + lr;
                    int tc = (ks * 4 + g) ^ ((lr & 7) ^ ((dt * 2 + (lr >> 3)) & 7));
                    bf16x8 vf = *(const bf16x8*)&Vc[d * 128 + tc * 8];
                    O[0][dt] = __builtin_amdgcn_mfma_f32_16x16x32_bf16(pa0, vf, O[0][dt], 0, 0, 0);
                    O[1][dt] = __builtin_amdgcn_mfma_f32_16x16x32_bf16(pa1, vf, O[1][dt], 0, 0, 0);
                }
            }
            buf ^= 1;
        }

#pragma unroll
        for (int sub = 0; sub < 2; ++sub) {
            int lv = __builtin_bit_cast(int, l_[sub]);
#pragma unroll
            for (int r = 0; r < 4; ++r) {
                float lval = __builtin_bit_cast(float, __builtin_amdgcn_ds_bpermute(idxA[r], lv));
                float inv = __builtin_amdgcn_rcpf(lval);
                int q = q0w + sub * 16 + g * 4 + r;
#pragma unroll
                for (int dt = 0; dt < 4; ++dt)
                    y[(size_t)(b * 2048 + q) * 1024 + h * 64 + dt * 16 + lr] =
                        f2bf(O[sub][dt][r] * inv);
            }
        }
    };

    process(15 - p);
    __syncthreads();
    process(p);
}

// ------ residual + layernorm: out = base + LN(d1 + d2)*g+b; d1,d2 bf16 ------
// base f32 (BASEBF=0) or bf16 (BASEBF=1)
template <int WRITE_BF, int BASEBF>
__global__ __launch_bounds__(256) void ln_kernel(const void* __restrict__ base,
                                                 const unsigned short* __restrict__ d1,
                                                 const unsigned short* __restrict__ d2,
                                                 const float* __restrict__ gw,
                                                 const float* __restrict__ bw,
                                                 float* __restrict__ outf,
                                                 unsigned short* __restrict__ outb) {
    const int row = blockIdx.x;
    const int tid = threadIdx.x;
    ushort4 u1 = *(const ushort4*)&d1[(size_t)row * 1024 + tid * 4];
    ushort4 u2 = *(const ushort4*)&d2[(size_t)row * 1024 + tid * 4];
    float4 x;
    x.x = bf2f(u1.x) + bf2f(u2.x);
    x.y = bf2f(u1.y) + bf2f(u2.y);
    x.z = bf2f(u1.z) + bf2f(u2.z);
    x.w = bf2f(u1.w) + bf2f(u2.w);
    float s = x.x + x.y + x.z + x.w;
    float s2 = x.x * x.x + x.y * x.y + x.z * x.z + x.w * x.w;
#pragma unroll
    for (int off = 1; off < 64; off <<= 1) {
        s += __shfl_xor(s, off);
        s2 += __shfl_xor(s2, off);
    }
    __shared__ float red[8];
    if ((tid & 63) == 0) {
        red[tid >> 6] = s;
        red[4 + (tid >> 6)] = s2;
    }
    __syncthreads();
    s = red[0] + red[1] + red[2] + red[3];
    s2 = red[4] + red[5] + red[6] + red[7];
    float mu = s * (1.f / 1024.f);
    float var = s2 * (1.f / 1024.f) - mu * mu;
    float rsig = rsqrtf(var + 1e-5f);
    float4 bb;
    if (BASEBF) {
        const unsigned short* bs = (const unsigned short*)base + (size_t)row * 1024 + tid * 4;
        ushort4 u = *(const ushort4*)bs;
        bb.x = bf2f(u.x); bb.y = bf2f(u.y); bb.z = bf2f(u.z); bb.w = bf2f(u.w);
    } else {
        bb = *(const float4*)((const float*)base + (size_t)row * 1024 + tid * 4);
    }
    float4 gv = *(const float4*)&gw[tid * 4];
    float4 bv = *(const float4*)&bw[tid * 4];
    float4 o;
    o.x = bb.x + (x.x - mu) * rsig * gv.x + bv.x;
    o.y = bb.y + (x.y - mu) * rsig * gv.y + bv.y;
    o.z = bb.z + (x.z - mu) * rsig * gv.z + bv.z;
    o.w = bb.w + (x.w - mu) * rsig * gv.w + bv.w;
    if (outf) *(float4*)&outf[(size_t)row * 1024 + tid * 4] = o;
    if (WRITE_BF) {
        unsigned short* ob = outb + (size_t)row * 1024 + tid * 4;
        ob[0] = f2bf(o.x);
        ob[1] = f2bf(o.y);
        ob[2] = f2bf(o.z);
        ob[3] = f2bf(o.w);
    }
}

extern "C" void kernel_launch(void* const* d_in, const int* in_sizes, int n_in,
                              void* d_out, int out_size, void* d_ws, size_t ws_size,
                              hipStream_t stream) {
    const float* x = (const float*)d_in[0];
    const float* w_qkv = (const float*)d_in[1];
    const float* b_qkv = (const float*)d_in[2];
    const float* w_out = (const float*)d_in[3];
    const float* b_out = (const float*)d_in[4];
    const float* w1 = (const float*)d_in[5];
    const float* b1 = (const float*)d_in[6];
    const float* w2 = (const float*)d_in[7];
    const float* b2 = (const float*)d_in[8];
    const float* g1 = (const float*)d_in[9];
    const float* be1 = (const float*)d_in[10];
    const float* g2 = (const float*)d_in[11];
    const float* be2 = (const float*)d_in[12];

    const size_t MB = 1ull << 20;
    if (ws_size < 184 * MB) return;
    char* ws = (char*)d_ws;
    // live-range-checked layout (all inter-kernel activations bf16):
    unsigned short* xb    = (unsigned short*)(ws + 0);         // 0-16   cvt -> qkv
    unsigned short* vtg   = (unsigned short*)(ws + 0);         // 0-16   vtrans -> attn
    unsigned short* attnp1= (unsigned short*)(ws + 0);         // 0-16   outproj -> ln1 (bf16)
    unsigned short* hb    = (unsigned short*)(ws + 0);         // 0-64   mlp1 -> mlp2 (after ln1)
    unsigned short* wqkvt = (unsigned short*)(ws + 16 * MB);   // 16-22  -> qkv
    unsigned short* qkvb  = (unsigned short*)(ws + 22 * MB);   // 22-70  qkv -> attn
    unsigned short* woutt = (unsigned short*)(ws + 70 * MB);   // 70-72  -> outproj
    unsigned short* yb    = (unsigned short*)(ws + 72 * MB);   // 72-88  attn -> outproj
    unsigned short* ff1b  = (unsigned short*)(ws + 72 * MB);   // 72-88  mlp2 -> ln2 (bf16)
    unsigned short* attnp = (unsigned short*)(ws + 88 * MB);   // 88-104 outproj -> ln1 (bf16)
    unsigned short* ffb   = (unsigned short*)(ws + 88 * MB);   // 88-104 mlp2 -> ln2 (bf16)
    unsigned short* x2b   = (unsigned short*)(ws + 152 * MB);  // 152-168 ln1 -> mlp1, ln2
    unsigned short* w1t   = (unsigned short*)(ws + 168 * MB);  // 168-176 -> mlp1
    unsigned short* w2t   = (unsigned short*)(ws + 176 * MB);  // 176-184 -> mlp2

    // prep
    cvtbf_kernel<<<8192, 256, 0, stream>>>(x, xb);
    transpose_cvt_kernel<<<dim3(96, 32), dim3(32, 8), 0, stream>>>(w_qkv, wqkvt, 1024, 3072);
    transpose_cvt_kernel<<<dim3(32, 32), dim3(32, 8), 0, stream>>>(w_out, woutt, 1024, 1024);
    transpose_cvt_kernel<<<dim3(128, 32), dim3(32, 8), 0, stream>>>(w1, w1t, 1024, 4096);
    transpose_cvt_kernel<<<dim3(32, 128), dim3(32, 8), 0, stream>>>(w2, w2t, 4096, 1024);
    // qkv = x @ w_qkv + b_qkv (bf16) [8192x3072, K=1024]: 32mt x 12nt, GM=4
    gemm256_kernel<0, 1, 1><<<384, 512, 0, stream>>>(xb, wqkvt, b_qkv, qkvb, nullptr,
                                                     3072, 1024, 12, 4, 1);
    // V^T pre-transpose
    vtrans_kernel<<<dim3(32, 64), 256, 0, stream>>>(qkvb, vtg);
    // attention
    attn_kernel<<<dim3(8, 16, 4), 256, 0, stream>>>(qkvb, vtg, yb);
    // out proj (bf16 + bf16 partial, split-K=2) [8192x1024, K=1024]: 2sl x 32mt x 4nt, GM=8
    gemm256_kernel<0, 1, 1><<<256, 512, 0, stream>>>(yb, woutt, b_out, attnp, attnp1,
                                                     1024, 1024, 4, 8, 2);
    // x2b = bf16(x + LN(attnp + attnp1))
    ln_kernel<1, 0><<<8192, 256, 0, stream>>>(x, attnp, attnp1, g1, be1, nullptr, x2b);
    // h = gelu(x2 @ w1 + b1) (bf16) [8192x4096, K=1024]: 32mt x 16nt, GM=4
    gemm256_kernel<1, 1, 1><<<512, 512, 0, stream>>>(x2b, w1t, b1, hb, nullptr,
                                                     4096, 1024, 16, 4, 1);
    // f = h @ w2 + b2 (bf16 + bf16 partial, split-K=2) [8192x1024, K=4096]: 2sl x 32mt x 4nt, GM=8
    gemm256_kernel<0, 1, 1><<<256, 512, 0, stream>>>(hb, w2t, b2, ffb, ff1b,
                                                     1024, 4096, 4, 8, 2);
    // out = x2b + LN(ffb + ff1b)   (f32 out)
    ln_kernel<0, 1><<<8192, 256, 0, stream>>>(x2b, ffb, ff1b, g2, be2, (float*)d_out, nullptr);
}

// Round 19
// 437.598 us; speedup vs baseline: 1.0379x; 1.0169x over previous
//
#include <hip/hip_runtime.h>
#include <hip/hip_bf16.h>

typedef unsigned short ushort_t;
using bf16x8 = __attribute__((ext_vector_type(8))) short;
using f32x4  = __attribute__((ext_vector_type(4))) float;

#define DEV __device__ __forceinline__

DEV unsigned short f2bf(float f) {
    unsigned int u = __builtin_bit_cast(unsigned int, f);
    u = (u + 0x7fffu + ((u >> 16) & 1u)) >> 16;
    return (unsigned short)u;
}

DEV float bf2f(unsigned short s) {
    return __builtin_bit_cast(float, (unsigned int)s << 16);
}

DEV int cvtpk_bf16(float lo, float hi) {
    int r;
    asm("v_cvt_pk_bf16_f32 %0, %1, %2" : "=v"(r) : "v"(lo), "v"(hi));
    return r;
}

DEV void gload16(const unsigned short* g, unsigned short* l) {
    __builtin_amdgcn_global_load_lds(
        (const __attribute__((address_space(1))) void*)g,
        (__attribute__((address_space(3))) void*)l, 16, 0, 0);
}

// sigmoid-form GELU: v*sigmoid(1.702v); max err ~0.02 abs (threshold 0.18)
DEV float gelu_f(float v) {
    float t = __builtin_amdgcn_exp2f(v * 2.4554946f);
    return v * t * __builtin_amdgcn_rcpf(t + 1.0f);
}

// ---------------- f32 -> bf16 convert ----------------
__global__ __launch_bounds__(256) void cvtbf_kernel(const float* __restrict__ in,
                                                    unsigned short* __restrict__ out) {
    int i = (blockIdx.x * 256 + threadIdx.x) * 4;
    float4 v = *(const float4*)&in[i];
    out[i + 0] = f2bf(v.x);
    out[i + 1] = f2bf(v.y);
    out[i + 2] = f2bf(v.z);
    out[i + 3] = f2bf(v.w);
}

// -------- fused transpose+convert for all 4 weight matrices (one launch) ----------
// tile body identical to the R17 transpose_cvt_kernel; block range selects matrix.
// m0: w_qkv 1024x3072 (96x32 tiles)   [0,    3072)
// m1: w_out 1024x1024 (32x32)         [3072, 4096)
// m2: w1    1024x4096 (128x32)        [4096, 8192)
// m3: w2    4096x1024 (32x128)        [8192, 12288)
__global__ __launch_bounds__(256) void transpose4_kernel(
    const float* __restrict__ s0, unsigned short* __restrict__ d0,
    const float* __restrict__ s1, unsigned short* __restrict__ d1,
    const float* __restrict__ s2, unsigned short* __restrict__ d2,
    const float* __restrict__ s3, unsigned short* __restrict__ d3) {
    __shared__ float t[32][33];
    const int tx = threadIdx.x, ty = threadIdx.y;
    int bid = blockIdx.x;
    const float* in;
    unsigned short* out;
    int R, C, bx, by;
    if (bid < 3072)      { in = s0; out = d0; R = 1024; C = 3072; bx = bid % 96;  by = bid / 96; }
    else if (bid < 4096) { bid -= 3072; in = s1; out = d1; R = 1024; C = 1024; bx = bid % 32;  by = bid / 32; }
    else if (bid < 8192) { bid -= 4096; in = s2; out = d2; R = 1024; C = 4096; bx = bid % 128; by = bid / 128; }
    else                 { bid -= 8192; in = s3; out = d3; R = 4096; C = 1024; bx = bid % 32;  by = bid / 32; }
    const int c0 = bx * 32, r0 = by * 32;
#pragma unroll
    for (int i = 0; i < 4; ++i)
        t[ty + i * 8][tx] = in[(size_t)(r0 + ty + i * 8) * C + c0 + tx];
    __syncthreads();
#pragma unroll
    for (int i = 0; i < 4; ++i)
        out[(size_t)(c0 + ty + i * 8) * R + r0 + tx] = f2bf(t[tx][ty + i * 8]);
}

// ---------------- V transpose: qkvb V-part -> vtg[bh][64][2048] bf16 ----------------
__global__ __launch_bounds__(256) void vtrans_kernel(const unsigned short* __restrict__ qkvb,
                                                     unsigned short* __restrict__ vtg) {
    __shared__ unsigned short t[64 * 66];
    const int tid = threadIdx.x;
    const int t0 = blockIdx.x * 64;
    const int bh = blockIdx.y;
    const int b = bh >> 4, h = bh & 15;
    const unsigned short* src = qkvb + (size_t)(b * 2048 + t0) * 3072 + 2048 + h * 64;
#pragma unroll
    for (int c = 0; c < 2; ++c) {
        int cid = c * 256 + tid;
        int row = cid >> 3, cc = cid & 7;
        *(int4*)&t[row * 66 + cc * 8] = *(const int4*)&src[(size_t)row * 3072 + cc * 8];
    }
    __syncthreads();
    unsigned short* dst = vtg + (size_t)bh * 64 * 2048 + t0;
#pragma unroll
    for (int c = 0; c < 2; ++c) {
        int cid = c * 256 + tid;
        int d = cid >> 3, cc2 = cid & 7;
        bf16x8 v;
#pragma unroll
        for (int j = 0; j < 8; ++j) v[j] = (short)t[(cc2 * 8 + j) * 66 + d];
        *(bf16x8*)&dst[(size_t)d * 2048 + cc2 * 8] = v;
    }
}

// ---------------- GEMM 256x256, BK=64, 8 waves (2Mx4N), R8/R11 4-phase schedule -----
template <int ACT, int OBF, int OBF2>
__global__ __launch_bounds__(512, 2) void gemm256_kernel(
    const unsigned short* __restrict__ A, const unsigned short* __restrict__ Bt,
    const float* __restrict__ bias, void* __restrict__ out, void* __restrict__ out2,
    int N, int Ktot, int gridNt, int GM, int nSlices) {
    __shared__ __align__(16) unsigned short lA[2][256 * 64];
    __shared__ __align__(16) unsigned short lB[2][256 * 64];
    const int tid = threadIdx.x;
    const int lane = tid & 63, wid = tid >> 6;
    const int g = lane >> 4, lr = lane & 15;
    const int wm = wid >> 2, wn = wid & 3;

    const int nwg = gridDim.x, cpx = nwg >> 3, bid = blockIdx.x;
    const int wkid = (bid & 7) * cpx + (bid >> 3);
    const int bps = nwg / nSlices;
    const int sl = wkid / bps, rem = wkid % bps;
    const int mt = (rem / (GM * gridNt)) * GM + (rem % GM);
    const int nt = (rem / GM) % gridNt;
    const int m0 = mt * 256, n0 = nt * 256;
    const int Ksl = Ktot / nSlices;
    const int kb0 = sl * Ksl;
    const int nkt = Ksl >> 6;
    void* outp = (sl == 0) ? out : out2;

    auto stageA = [&](int s, int kt, int bb) {  // s in [0,4): covers kb 2s..2s+1
        int c = s * 512 + tid;
        int row = c & 255, kb = c >> 8;
        gload16(&A[(size_t)(m0 + row) * Ktot + kb0 + kt * 64 + kb * 8],
                &lA[bb][(size_t)(s * 512 + (tid & ~63)) * 8]);
    };
    auto stageB = [&](int s, int kt, int bb) {
        int c = s * 512 + tid;
        int row = c & 255, kb = c >> 8;
        gload16(&Bt[(size_t)(n0 + row) * Ktot + kb0 + kt * 64 + kb * 8],
                &lB[bb][(size_t)(s * 512 + (tid & ~63)) * 8]);
    };

    f32x4 acc[8][4] = {};
    bf16x8 bfr[4];

    // prologue: tile 0 in group order {A01}{B01}{A23}{B23}
    stageA(0, 0, 0); stageA(1, 0, 0); stageB(0, 0, 0); stageB(1, 0, 0);
    stageA(2, 0, 0); stageA(3, 0, 0); stageB(2, 0, 0); stageB(3, 0, 0);
    asm volatile("s_waitcnt vmcnt(4)" ::: "memory");
    __builtin_amdgcn_s_barrier();
    asm volatile("" ::: "memory");

    for (int kt = 0; kt < nkt; ++kt) {
        const int buf = kt & 1;
        const bool more = (kt + 1 < nkt);
#pragma unroll
        for (int p = 0; p < 4; ++p) {
            const int ks = p >> 1, mh = p & 1;
            bf16x8 af[4];
#pragma unroll
            for (int mf2 = 0; mf2 < 4; ++mf2) {
                int c = (ks * 4 + g) * 256 + wm * 128 + (mh * 4 + mf2) * 16 + lr;
                af[mf2] = *(const bf16x8*)&lA[buf][(size_t)c * 8];
            }
            if (mh == 0) {
#pragma unroll
                for (int nf = 0; nf < 4; ++nf) {
                    int c = (ks * 4 + g) * 256 + wn * 64 + nf * 16 + lr;
                    bfr[nf] = *(const bf16x8*)&lB[buf][(size_t)c * 8];
                }
            }
            if (more) {
                if (p == 0)      { stageA(0, kt + 1, buf ^ 1); stageA(1, kt + 1, buf ^ 1); }
                else if (p == 1) { stageB(0, kt + 1, buf ^ 1); stageB(1, kt + 1, buf ^ 1); }
                else if (p == 2) { stageA(2, kt + 1, buf ^ 1); stageA(3, kt + 1, buf ^ 1); }
                else             { stageB(2, kt + 1, buf ^ 1); stageB(3, kt + 1, buf ^ 1); }
            }
            __builtin_amdgcn_s_barrier();
            asm volatile("s_waitcnt lgkmcnt(0)" ::: "memory");
            __builtin_amdgcn_sched_barrier(0);
            __builtin_amdgcn_s_setprio(1);
#pragma unroll
            for (int mf2 = 0; mf2 < 4; ++mf2)
#pragma unroll
                for (int nf = 0; nf < 4; ++nf)
                    acc[mh * 4 + mf2][nf] = __builtin_amdgcn_mfma_f32_16x16x32_bf16(
                        af[mf2], bfr[nf], acc[mh * 4 + mf2][nf], 0, 0, 0);
            __builtin_amdgcn_s_setprio(0);
            __builtin_amdgcn_sched_barrier(0);
            if (p == 1) {
                if (more) asm volatile("s_waitcnt vmcnt(4)" ::: "memory");
                else      asm volatile("s_waitcnt vmcnt(0)" ::: "memory");
            } else if (p == 3) {
                if (more) asm volatile("s_waitcnt vmcnt(4)" ::: "memory");
            }
            __builtin_amdgcn_s_barrier();
            asm volatile("" ::: "memory");
        }
    }

    // epilogue: bias (slice 0 only) + optional GELU, store
#pragma unroll
    for (int mf = 0; mf < 8; ++mf) {
#pragma unroll
        for (int nf = 0; nf < 4; ++nf) {
            int col = n0 + wn * 64 + nf * 16 + lr;
            float bv = (sl == 0) ? bias[col] : 0.0f;
#pragma unroll
            for (int r = 0; r < 4; ++r) {
                int row = m0 + wm * 128 + mf * 16 + g * 4 + r;
                float v = acc[mf][nf][r] + bv;
                if (ACT == 1) v = gelu_f(v);
                if (sl == 0) {
                    if (OBF)
                        ((unsigned short*)outp)[(size_t)row * N + col] = f2bf(v);
                    else
                        ((float*)outp)[(size_t)row * N + col] = v;
                } else {
                    if (OBF2)
                        ((unsigned short*)outp)[(size_t)row * N + col] = f2bf(v);
                    else
                        ((float*)outp)[(size_t)row * N + col] = v;
                }
            }
        }
    }
}

// ---------------- flash attention v4: KVBLK=128, defer-max, bh->XCD affinity --------
__global__ __launch_bounds__(256, 2) void attn_kernel(const unsigned short* __restrict__ qkv,
                                                      const unsigned short* __restrict__ vtg,
                                                      unsigned short* __restrict__ y) {
    __shared__ unsigned short Kl[2][128 * 64];
    __shared__ unsigned short Vl[2][64 * 128];
    const int tid = threadIdx.x, lane = tid & 63, w = tid >> 6;
    const int g = lane >> 4, lr = lane & 15;
    const int id = blockIdx.x + 8 * (blockIdx.y + 16 * blockIdx.z);
    const int xcd = id & 7, wrk = id >> 3;
    const int bh = xcd * 8 + (wrk & 7);
    const int p = wrk >> 3;
    const int b = bh >> 4, h = bh & 15;
    const size_t rs3 = 3072;
    const unsigned short* qbase = qkv + (size_t)b * 2048 * rs3 + h * 64;
    const unsigned short* kbase = qbase + 1024;
    const unsigned short* vbase = vtg + (size_t)bh * 64 * 2048;

    int ksoff[4], vsoff[4], ldoff[4];
#pragma unroll
    for (int c = 0; c < 4; ++c) {
        int cid = c * 256 + tid;
        int krow = cid >> 3, kcc = cid & 7;
        ksoff[c] = krow * 3072 + (kcc ^ (krow & 7) ^ ((krow >> 3) & 7)) * 8;
        int d = cid >> 4, tcs = cid & 15;
        vsoff[c] = d * 2048 + (tcs ^ ((d & 7) ^ ((d >> 3) & 7))) * 8;
        ldoff[c] = (c * 256 + (tid & ~63)) * 8;
    }

    const int idxP0 = 4 * (32 * (g & 1) + lr);
    const int idxP1 = idxP0 + 64;
    int idxA[4];
#pragma unroll
    for (int r = 0; r < 4; ++r) idxA[r] = 4 * (g * 20 + r);
    const bool ghigh = (g >> 1) != 0;
    const float qscale = 0.125f * 1.44269504089f;

    auto process = [&](int J) {
        const int q0w = J * 128 + w * 32;
        const int ktend = J + 1;
#pragma unroll
        for (int c = 0; c < 4; ++c) {
            gload16(&kbase[ksoff[c]], &Kl[0][ldoff[c]]);
            gload16(&vbase[vsoff[c]], &Vl[0][ldoff[c]]);
        }
        int qf[2][2][4];
#pragma unroll
        for (int sub = 0; sub < 2; ++sub)
#pragma unroll
            for (int f = 0; f < 2; ++f) {
                int4 v = *(const int4*)&qbase[(size_t)(q0w + sub * 16 + lr) * rs3 + f * 32 + g * 8];
                int vv[4] = {v.x, v.y, v.z, v.w};
#pragma unroll
                for (int i = 0; i < 4; ++i) {
                    unsigned int u = (unsigned int)vv[i];
                    float lo = __builtin_bit_cast(float, u << 16) * qscale;
                    float hi = __builtin_bit_cast(float, u & 0xffff0000u) * qscale;
                    qf[sub][f][i] = cvtpk_bf16(lo, hi);
                }
            }

        f32x4 O[2][4] = {};
        float m_[2] = {-3.0e38f, -3.0e38f}, l_[2] = {0.f, 0.f};

        int buf = 0;
        for (int kt = 0; kt < ktend; ++kt) {
            asm volatile("s_waitcnt vmcnt(0)" ::: "memory");
            __builtin_amdgcn_s_barrier();
            asm volatile("" ::: "memory");
            if (kt + 1 < ktend) {
#pragma unroll
                for (int c = 0; c < 4; ++c) {
                    gload16(&kbase[(size_t)(kt + 1) * 128 * 3072 + ksoff[c]], &Kl[buf ^ 1][ldoff[c]]);
                    gload16(&vbase[vsoff[c] + (kt + 1) * 128], &Vl[buf ^ 1][ldoff[c]]);
                }
            }
            const unsigned short* Kc = Kl[buf];
            const unsigned short* Vc = Vl[buf];

            f32x4 s0[8], s1[8];
#pragma unroll
            for (int st = 0; st < 8; ++st) {
                int rbase = (st * 16 + lr) * 64;
                int sw = (lr & 7) ^ ((st * 2 + (lr >> 3)) & 7);
                bf16x8 kf0 = *(const bf16x8*)&Kc[rbase + ((g ^ sw) * 8)];
                bf16x8 kf1 = *(const bf16x8*)&Kc[rbase + (((4 + g) ^ sw) * 8)];
                f32x4 a = {};
                a = __builtin_amdgcn_mfma_f32_16x16x32_bf16(kf0, *(const bf16x8*)&qf[0][0], a, 0, 0, 0);
                a = __builtin_amdgcn_mfma_f32_16x16x32_bf16(kf1, *(const bf16x8*)&qf[0][1], a, 0, 0, 0);
                s0[st] = a;
                f32x4 c = {};
                c = __builtin_amdgcn_mfma_f32_16x16x32_bf16(kf0, *(const bf16x8*)&qf[1][0], c, 0, 0, 0);
                c = __builtin_amdgcn_mfma_f32_16x16x32_bf16(kf1, *(const bf16x8*)&qf[1][1], c, 0, 0, 0);
                s1[st] = c;
            }

            int wt0[4][4], wt1[4][4];
#pragma unroll
            for (int sub = 0; sub < 2; ++sub) {
                f32x4* s = (sub == 0) ? s0 : s1;
                const int qmin = q0w + sub * 16;
                if (kt == J) {
                    int qv = qmin + lr;
#pragma unroll
                    for (int st = 0; st < 8; ++st) {
                        int keyb = kt * 128 + st * 16 + g * 4;
#pragma unroll
                        for (int r = 0; r < 4; ++r)
                            if (keyb + r > qv) s[st][r] = -3.0e38f;
                    }
                }
                float mx = fmaxf(fmaxf(s[0][0], s[0][1]), fmaxf(s[0][2], s[0][3]));
#pragma unroll
                for (int st = 1; st < 8; ++st)
                    mx = fmaxf(mx, fmaxf(fmaxf(s[st][0], s[st][1]), fmaxf(s[st][2], s[st][3])));
                mx = fmaxf(mx, __shfl_xor(mx, 16));
                mx = fmaxf(mx, __shfl_xor(mx, 32));
                if (__any(mx - m_[sub] > 11.5f)) {
                    float mnew = fmaxf(m_[sub], mx);
                    float alpha = __builtin_amdgcn_exp2f(m_[sub] - mnew);
                    m_[sub] = mnew;
                    l_[sub] *= alpha;
                    int av = __builtin_bit_cast(int, alpha);
                    f32x4* Os = O[sub];
#pragma unroll
                    for (int r = 0; r < 4; ++r) {
                        float ar = __builtin_bit_cast(float, __builtin_amdgcn_ds_bpermute(idxA[r], av));
#pragma unroll
                        for (int dt = 0; dt < 4; ++dt) Os[dt][r] *= ar;
                    }
                }
                float rs = 0.f;
#pragma unroll
                for (int st = 0; st < 8; ++st)
#pragma unroll
                    for (int r = 0; r < 4; ++r) {
                        float pp = __builtin_amdgcn_exp2f(s[st][r] - m_[sub]);
                        s[st][r] = pp;
                        rs += pp;
                    }
                rs += __shfl_xor(rs, 16);
                rs += __shfl_xor(rs, 32);
                l_[sub] += rs;
                int ws_[8][2];
#pragma unroll
                for (int st = 0; st < 8; ++st) {
                    ws_[st][0] = cvtpk_bf16(s[st][0], s[st][1]);
                    ws_[st][1] = cvtpk_bf16(s[st][2], s[st][3]);
                }
                int(*wt)[4] = (sub == 0) ? wt0 : wt1;
#pragma unroll
                for (int ks = 0; ks < 4; ++ks)
#pragma unroll
                    for (int hp = 0; hp < 4; ++hp) {
                        int idx = (hp < 2) ? idxP0 : idxP1;
                        int v0 = __builtin_amdgcn_ds_bpermute(idx, ws_[2 * ks][hp & 1]);
                        int v1 = __builtin_amdgcn_ds_bpermute(idx, ws_[2 * ks + 1][hp & 1]);
                        wt[ks][hp] = ghigh ? v1 : v0;
                    }
            }

#pragma unroll
            for (int ks = 0; ks < 4; ++ks) {
                bf16x8 pa0 = *(const bf16x8*)&wt0[ks][0];
                bf16x8 pa1 = *(const bf16x8*)&wt1[ks][0];
#pragma unroll
                for (int dt = 0; dt < 4; ++dt) {
                    int d = dt * 16 + lr;
                    int tc = (ks * 4 + g) ^ ((lr & 7) ^ ((dt * 2 + (lr >> 3)) & 7));
                    bf16x8 vf = *(const bf16x8*)&Vc[d * 128 + tc * 8];
                    O[0][dt] = __builtin_amdgcn_mfma_f32_16x16x32_bf16(pa0, vf, O[0][dt], 0, 0, 0);
                    O[1][dt] = __builtin_amdgcn_mfma_f32_16x16x32_bf16(pa1, vf, O[1][dt], 0, 0, 0);
                }
            }
            buf ^= 1;
        }

#pragma unroll
        for (int sub = 0; sub < 2; ++sub) {
            int lv = __builtin_bit_cast(int, l_[sub]);
#pragma unroll
            for (int r = 0; r < 4; ++r) {
                float lval = __builtin_bit_cast(float, __builtin_amdgcn_ds_bpermute(idxA[r], lv));
                float inv = __builtin_amdgcn_rcpf(lval);
                int q = q0w + sub * 16 + g * 4 + r;
#pragma unroll
                for (int dt = 0; dt < 4; ++dt)
                    y[(size_t)(b * 2048 + q) * 1024 + h * 64 + dt * 16 + lr] =
                        f2bf(O[sub][dt][r] * inv);
            }
        }
    };

    process(15 - p);
    __syncthreads();
    process(p);
}

// ------ residual + layernorm: out = base + LN(d1 + d2)*g+b; d1,d2 bf16 ------
// base f32 (BASEBF=0) or bf16 (BASEBF=1)
template <int WRITE_BF, int BASEBF>
__global__ __launch_bounds__(256) void ln_kernel(const void* __restrict__ base,
                                                 const unsigned short* __restrict__ d1,
                                                 const unsigned short* __restrict__ d2,
                                                 const float* __restrict__ gw,
                                                 const float* __restrict__ bw,
                                                 float* __restrict__ outf,
                                                 unsigned short* __restrict__ outb) {
    const int row = blockIdx.x;
    const int tid = threadIdx.x;
    ushort4 u1 = *(const ushort4*)&d1[(size_t)row * 1024 + tid * 4];
    ushort4 u2 = *(const ushort4*)&d2[(size_t)row * 1024 + tid * 4];
    float4 x;
    x.x = bf2f(u1.x) + bf2f(u2.x);
    x.y = bf2f(u1.y) + bf2f(u2.y);
    x.z = bf2f(u1.z) + bf2f(u2.z);
    x.w = bf2f(u1.w) + bf2f(u2.w);
    float s = x.x + x.y + x.z + x.w;
    float s2 = x.x * x.x + x.y * x.y + x.z * x.z + x.w * x.w;
#pragma unroll
    for (int off = 1; off < 64; off <<= 1) {
        s += __shfl_xor(s, off);
        s2 += __shfl_xor(s2, off);
    }
    __shared__ float red[8];
    if ((tid & 63) == 0) {
        red[tid >> 6] = s;
        red[4 + (tid >> 6)] = s2;
    }
    __syncthreads();
    s = red[0] + red[1] + red[2] + red[3];
    s2 = red[4] + red[5] + red[6] + red[7];
    float mu = s * (1.f / 1024.f);
    float var = s2 * (1.f / 1024.f) - mu * mu;
    float rsig = rsqrtf(var + 1e-5f);
    float4 bb;
    if (BASEBF) {
        const unsigned short* bs = (const unsigned short*)base + (size_t)row * 1024 + tid * 4;
        ushort4 u = *(const ushort4*)bs;
        bb.x = bf2f(u.x); bb.y = bf2f(u.y); bb.z = bf2f(u.z); bb.w = bf2f(u.w);
    } else {
        bb = *(const float4*)((const float*)base + (size_t)row * 1024 + tid * 4);
    }
    float4 gv = *(const float4*)&gw[tid * 4];
    float4 bv = *(const float4*)&bw[tid * 4];
    float4 o;
    o.x = bb.x + (x.x - mu) * rsig * gv.x + bv.x;
    o.y = bb.y + (x.y - mu) * rsig * gv.y + bv.y;
    o.z = bb.z + (x.z - mu) * rsig * gv.z + bv.z;
    o.w = bb.w + (x.w - mu) * rsig * gv.w + bv.w;
    if (outf) *(float4*)&outf[(size_t)row * 1024 + tid * 4] = o;
    if (WRITE_BF) {
        unsigned short* ob = outb + (size_t)row * 1024 + tid * 4;
        ob[0] = f2bf(o.x);
        ob[1] = f2bf(o.y);
        ob[2] = f2bf(o.z);
        ob[3] = f2bf(o.w);
    }
}

extern "C" void kernel_launch(void* const* d_in, const int* in_sizes, int n_in,
                              void* d_out, int out_size, void* d_ws, size_t ws_size,
                              hipStream_t stream) {
    const float* x = (const float*)d_in[0];
    const float* w_qkv = (const float*)d_in[1];
    const float* b_qkv = (const float*)d_in[2];
    const float* w_out = (const float*)d_in[3];
    const float* b_out = (const float*)d_in[4];
    const float* w1 = (const float*)d_in[5];
    const float* b1 = (const float*)d_in[6];
    const float* w2 = (const float*)d_in[7];
    const float* b2 = (const float*)d_in[8];
    const float* g1 = (const float*)d_in[9];
    const float* be1 = (const float*)d_in[10];
    const float* g2 = (const float*)d_in[11];
    const float* be2 = (const float*)d_in[12];

    const size_t MB = 1ull << 20;
    if (ws_size < 184 * MB) return;
    char* ws = (char*)d_ws;
    // live-range-checked layout (all inter-kernel activations bf16):
    unsigned short* xb    = (unsigned short*)(ws + 0);         // 0-16   cvt -> qkv
    unsigned short* vtg   = (unsigned short*)(ws + 0);         // 0-16   vtrans -> attn
    unsigned short* attnp1= (unsigned short*)(ws + 0);         // 0-16   outproj -> ln1 (bf16)
    unsigned short* hb    = (unsigned short*)(ws + 0);         // 0-64   mlp1 -> mlp2 (after ln1)
    unsigned short* wqkvt = (unsigned short*)(ws + 16 * MB);   // 16-22  -> qkv
    unsigned short* qkvb  = (unsigned short*)(ws + 22 * MB);   // 22-70  qkv -> attn
    unsigned short* woutt = (unsigned short*)(ws + 70 * MB);   // 70-72  -> outproj
    unsigned short* yb    = (unsigned short*)(ws + 72 * MB);   // 72-88  attn -> outproj
    unsigned short* ff1b  = (unsigned short*)(ws + 72 * MB);   // 72-88  mlp2 -> ln2 (bf16)
    unsigned short* attnp = (unsigned short*)(ws + 88 * MB);   // 88-104 outproj -> ln1 (bf16)
    unsigned short* ffb   = (unsigned short*)(ws + 88 * MB);   // 88-104 mlp2 -> ln2 (bf16)
    unsigned short* x2b   = (unsigned short*)(ws + 152 * MB);  // 152-168 ln1 -> mlp1, ln2
    unsigned short* w1t   = (unsigned short*)(ws + 168 * MB);  // 168-176 -> mlp1
    unsigned short* w2t   = (unsigned short*)(ws + 176 * MB);  // 176-184 -> mlp2

    // prep (x convert + fused 4-way weight transpose)
    cvtbf_kernel<<<8192, 256, 0, stream>>>(x, xb);
    transpose4_kernel<<<12288, dim3(32, 8), 0, stream>>>(w_qkv, wqkvt, w_out, woutt,
                                                         w1, w1t, w2, w2t);
    // qkv = x @ w_qkv + b_qkv (bf16) [8192x3072, K=1024]: 32mt x 12nt, GM=4
    gemm256_kernel<0, 1, 1><<<384, 512, 0, stream>>>(xb, wqkvt, b_qkv, qkvb, nullptr,
                                                     3072, 1024, 12, 4, 1);
    // V^T pre-transpose
    vtrans_kernel<<<dim3(32, 64), 256, 0, stream>>>(qkvb, vtg);
    // attention
    attn_kernel<<<dim3(8, 16, 4), 256, 0, stream>>>(qkvb, vtg, yb);
    // out proj (bf16 + bf16 partial, split-K=2) [8192x1024, K=1024]: 2sl x 32mt x 4nt, GM=8
    gemm256_kernel<0, 1, 1><<<256, 512, 0, stream>>>(yb, woutt, b_out, attnp, attnp1,
                                                     1024, 1024, 4, 8, 2);
    // x2b = bf16(x + LN(attnp + attnp1))
    ln_kernel<1, 0><<<8192, 256, 0, stream>>>(x, attnp, attnp1, g1, be1, nullptr, x2b);
    // h = gelu(x2 @ w1 + b1) (bf16) [8192x4096, K=1024]: 32mt x 16nt, GM=4
    gemm256_kernel<1, 1, 1><<<512, 512, 0, stream>>>(x2b, w1t, b1, hb, nullptr,
                                                     4096, 1024, 16, 4, 1);
    // f = h @ w2 + b2 (bf16 + bf16 partial, split-K=2) [8192x1024, K=4096]: 2sl x 32mt x 4nt, GM=8
    gemm256_kernel<0, 1, 1><<<256, 512, 0, stream>>>(hb, w2t, b2, ffb, ff1b,
                                                     1024, 4096, 4, 8, 2);
    // out = x2b + LN(ffb + ff1b)   (f32 out)
    ln_kernel<0, 1><<<8192, 256, 0, stream>>>(x2b, ffb, ff1b, g2, be2, (float*)d_out, nullptr);
}